// Round 12
// baseline (404.559 us; speedup 1.0000x reference)
//
#include <hip/hip_runtime.h>

#define D_IN 128
#define D_HID 256
#define D_OUT 64
#define NGRAPH 64
#define BN_EPS 1e-5f
#define AGG_NPB 4   // nodes per block = 4 waves x 1 node/wave
#define POOL_ROWS 8 // LDS pool rows (graph span safety)

typedef __attribute__((ext_vector_type(8))) short bf16x8;
typedef __attribute__((ext_vector_type(4))) float f32x4;

__device__ inline unsigned short f2bf(float f) {
  unsigned u = __float_as_uint(f);
  return (unsigned short)((u + 0x7FFFu + ((u >> 16) & 1u)) >> 16);  // RNE
}
__device__ inline float bf2f(unsigned short h) {
  return __uint_as_float((unsigned)h << 16);
}

// ---------------- init: deg=1 (self loop), zero pooled/cnt/counter ----------------
__global__ void initK(int* outdeg, int* indeg, float* pooled, float* cnt, int* counter, int n) {
  int i = blockIdx.x * blockDim.x + threadIdx.x;
  if (i < n) { outdeg[i] = 1; indeg[i] = 1; }
  if (i < NGRAPH * D_OUT) pooled[i] = 0.f;
  if (i < NGRAPH) cnt[i] = 0.f;
  if (i == 0) *counter = 0;
}

// ---------------- degree count ----------------
__global__ void countK(const int* __restrict__ ei, int* outdeg, int* indeg, int E) {
  int e = blockIdx.x * blockDim.x + threadIdx.x;
  if (e >= E) return;
  atomicAdd(&outdeg[ei[e]], 1);      // row (out-degree, GCN norm base)
  atomicAdd(&indeg[ei[E + e]], 1);   // col (CSR segment length)
}

// ---------------- CSR range allocation: wave-scan + 1 atomic per wave ----------------
__global__ void allocK(const int* __restrict__ indeg, int* ptr, int* pos, int* counter, int n) {
  int i = blockIdx.x * blockDim.x + threadIdx.x;
  int lane = threadIdx.x & 63;
  int l = (i < n) ? indeg[i] : 0;
  int s = l;
  #pragma unroll
  for (int o = 1; o < 64; o <<= 1) {
    int v = __shfl_up(s, o);
    if (lane >= o) s += v;
  }
  int base = 0;
  if (lane == 63) base = atomicAdd(counter, s);  // lane63's inclusive = wave total
  base = __shfl(base, 63);
  if (i < n) { ptr[i] = base + s - l; pos[i] = base + s - l; }
}

// ---------------- CSR fill (edges + self loops), packed int2 {src, w-bits} ----
__global__ void fillK(const int* __restrict__ ei, const float* __restrict__ ea,
                      const int* __restrict__ outdeg, int* pos,
                      int2* __restrict__ csr, int E, int n) {
  int t = blockIdx.x * blockDim.x + threadIdx.x;
  if (t >= E + n) return;
  int r, c; float w;
  if (t < E) {
    r = ei[t]; c = ei[E + t];
    w = rsqrtf((float)outdeg[r]) * ea[t];
  } else {
    r = c = t - E;
    w = rsqrtf((float)outdeg[r]);   // self loop: ea = 1
  }
  int slot = atomicAdd(&pos[c], 1);
  csr[slot] = make_int2(r, __float_as_int(w));
}

// ---------------- prep: transpose weights to bf16 [col][k] ----------------
__global__ void prepK(const float* __restrict__ W1, const float* __restrict__ W2,
                      unsigned short* __restrict__ w1t, unsigned short* __restrict__ w2t) {
  int i = blockIdx.x * blockDim.x + threadIdx.x;
  if (i < D_IN * D_HID)  { int k = i >> 8, c = i & 255; w1t[c * D_IN + k]  = f2bf(W1[i]); }
  if (i < D_HID * D_OUT) { int k = i >> 6, c = i & 63;  w2t[c * D_HID + k] = f2bf(W2[i]); }
}

// ---------------- GEMM1 (bf16 MFMA) fused BN+ReLU: h1b = relu(bn(x@W1+b1)) ----
__global__ __launch_bounds__(256) void gemm1M(const float* __restrict__ x,
    const unsigned short* __restrict__ w1t,
    const float* __restrict__ b1, const float* __restrict__ g1,
    const float* __restrict__ be1, const float* __restrict__ m1, const float* __restrict__ v1,
    unsigned short* __restrict__ h1b, int n) {
  __shared__ __align__(16) short xs[64 * 128];
  __shared__ __align__(16) short ws[128 * 128];
  const int tid = threadIdx.x;
  const int row0 = blockIdx.x * 64;
  const int col0 = blockIdx.y * 128;
  #pragma unroll
  for (int it = 0; it < 4; ++it) {
    int id = it * 256 + tid;
    int r = id >> 4, c = id & 15;
    int gr = row0 + r;
    float f[8];
    if (gr < n) {
      float4 v0 = *(const float4*)&x[(size_t)gr * D_IN + c * 8];
      float4 v1 = *(const float4*)&x[(size_t)gr * D_IN + c * 8 + 4];
      f[0]=v0.x; f[1]=v0.y; f[2]=v0.z; f[3]=v0.w;
      f[4]=v1.x; f[5]=v1.y; f[6]=v1.z; f[7]=v1.w;
    } else {
      #pragma unroll
      for (int j = 0; j < 8; ++j) f[j] = 0.f;
    }
    bf16x8 pv;
    #pragma unroll
    for (int j = 0; j < 8; ++j) pv[j] = (short)f2bf(f[j]);
    *(bf16x8*)&xs[r * 128 + (c ^ (r & 15)) * 8] = pv;
  }
  #pragma unroll
  for (int it = 0; it < 8; ++it) {
    int id = it * 256 + tid;
    int r = id >> 4, c = id & 15;
    uint4 v = *(const uint4*)&w1t[(size_t)(col0 + r) * D_IN + c * 8];
    *(uint4*)&ws[r * 128 + (c ^ (r & 15)) * 8] = v;
  }
  __syncthreads();
  const int w = tid >> 6, l = tid & 63;
  const int m = l & 15, g = l >> 4;
  const int rbase = w * 16;
  f32x4 acc[8];
  #pragma unroll
  for (int i = 0; i < 8; ++i) acc[i] = (f32x4){0.f, 0.f, 0.f, 0.f};
  #pragma unroll
  for (int ks = 0; ks < 4; ++ks) {
    int ch = (ks * 4 + g) ^ m;
    bf16x8 A = *(bf16x8*)&xs[(rbase + m) * 128 + ch * 8];
    #pragma unroll
    for (int nt = 0; nt < 8; ++nt) {
      bf16x8 B = *(bf16x8*)&ws[(nt * 16 + m) * 128 + ch * 8];
      acc[nt] = __builtin_amdgcn_mfma_f32_16x16x32_bf16(A, B, acc[nt], 0, 0, 0);
    }
  }
  #pragma unroll
  for (int nt = 0; nt < 8; ++nt) {
    int c = col0 + nt * 16 + m;
    float As = g1[c] * rsqrtf(v1[c] + BN_EPS);
    float Bs = be1[c] + (b1[c] - m1[c]) * As;
    #pragma unroll
    for (int i = 0; i < 4; ++i) {
      int gr = row0 + rbase + g * 4 + i;
      if (gr < n) {
        float val = fmaxf(acc[nt][i] * As + Bs, 0.f);
        h1b[(size_t)gr * D_HID + c] = f2bf(val);
      }
    }
  }
}

// ---------------- GEMM2 (bf16 MFMA): h2b = bf16(h1b @ W2 + b2) ----------------
__global__ __launch_bounds__(256) void gemm2M(const unsigned short* __restrict__ h1b,
    const unsigned short* __restrict__ w2t, const float* __restrict__ b2,
    unsigned short* __restrict__ h2b, int n) {
  __shared__ __align__(16) short hs[64 * 128];
  __shared__ __align__(16) short ws[64 * 128];
  const int tid = threadIdx.x;
  const int row0 = blockIdx.x * 64;
  const int w = tid >> 6, l = tid & 63;
  const int m = l & 15, g = l >> 4;
  const int rbase = w * 16;
  f32x4 acc[4];
  #pragma unroll
  for (int i = 0; i < 4; ++i) acc[i] = (f32x4){0.f, 0.f, 0.f, 0.f};
  for (int ph = 0; ph < 2; ++ph) {
    int kbase = ph * 128;
    __syncthreads();
    #pragma unroll
    for (int it = 0; it < 4; ++it) {
      int id = it * 256 + tid;
      int r = id >> 4, c = id & 15;
      int gr = row0 + r;
      uint4 v = (uint4){0u, 0u, 0u, 0u};
      if (gr < n) v = *(const uint4*)&h1b[(size_t)gr * D_HID + kbase + c * 8];
      *(uint4*)&hs[r * 128 + (c ^ (r & 15)) * 8] = v;
    }
    #pragma unroll
    for (int it = 0; it < 4; ++it) {
      int id = it * 256 + tid;
      int r = id >> 4, c = id & 15;
      uint4 v = *(const uint4*)&w2t[(size_t)r * D_HID + kbase + c * 8];
      *(uint4*)&ws[r * 128 + (c ^ (r & 15)) * 8] = v;
    }
    __syncthreads();
    #pragma unroll
    for (int ks = 0; ks < 4; ++ks) {
      int ch = (ks * 4 + g) ^ m;
      bf16x8 A = *(bf16x8*)&hs[(rbase + m) * 128 + ch * 8];
      #pragma unroll
      for (int nt = 0; nt < 4; ++nt) {
        bf16x8 B = *(bf16x8*)&ws[(nt * 16 + m) * 128 + ch * 8];
        acc[nt] = __builtin_amdgcn_mfma_f32_16x16x32_bf16(A, B, acc[nt], 0, 0, 0);
      }
    }
  }
  #pragma unroll
  for (int nt = 0; nt < 4; ++nt) {
    int c = nt * 16 + m;
    float bb = b2[c];
    #pragma unroll
    for (int i = 0; i < 4; ++i) {
      int gr = row0 + rbase + g * 4 + i;
      if (gr < n) h2b[(size_t)gr * D_OUT + c] = f2bf(acc[nt][i] + bb);
    }
  }
}

// ---------------- aggregate: 1 node/wave, 4-edge ILP, bf16 h2 gather ----------
__global__ __launch_bounds__(256) void aggK(const unsigned short* __restrict__ h2b,
    const int* __restrict__ ptr, const int* __restrict__ indeg, const int* __restrict__ outdeg,
    const int2* __restrict__ csr, const int* __restrict__ batch,
    float* __restrict__ pooled, float* __restrict__ cnt, int n) {
  __shared__ float lpool[POOL_ROWS * D_OUT];
  __shared__ float lcnt[POOL_ROWS];
  const int tid = threadIdx.x;
  for (int i = tid; i < POOL_ROWS * D_OUT; i += 256) lpool[i] = 0.f;
  if (tid < POOL_ROWS) lcnt[tid] = 0.f;
  const int n0 = blockIdx.x * AGG_NPB;
  const int g0 = batch[n0 < n ? n0 : (n - 1)];
  __syncthreads();
  const int wave = tid >> 6, lane = tid & 63;
  const int i = n0 + wave;
  if (i < n) {
    const int start = ptr[i];
    const int len = indeg[i];
    float acc = 0.f;
    int s = 0;
    for (; s + 4 <= len; s += 4) {
      int2 e0 = csr[start + s];
      int2 e1 = csr[start + s + 1];
      int2 e2 = csr[start + s + 2];
      int2 e3 = csr[start + s + 3];
      float v0 = bf2f(h2b[(size_t)e0.x * D_OUT + lane]);
      float v1 = bf2f(h2b[(size_t)e1.x * D_OUT + lane]);
      float v2 = bf2f(h2b[(size_t)e2.x * D_OUT + lane]);
      float v3 = bf2f(h2b[(size_t)e3.x * D_OUT + lane]);
      acc = fmaf(__int_as_float(e0.y), v0, acc);
      acc = fmaf(__int_as_float(e1.y), v1, acc);
      acc = fmaf(__int_as_float(e2.y), v2, acc);
      acc = fmaf(__int_as_float(e3.y), v3, acc);
    }
    for (; s < len; ++s) {
      int2 e = csr[start + s];
      acc = fmaf(__int_as_float(e.y), bf2f(h2b[(size_t)e.x * D_OUT + lane]), acc);
    }
    float val = fmaxf(acc * rsqrtf((float)outdeg[i]), 0.f);
    int g = batch[i];
    int gl = g - g0;
    if (gl < POOL_ROWS) {
      atomicAdd(&lpool[gl * D_OUT + lane], val);
      if (lane == 0) atomicAdd(&lcnt[gl], 1.f);
    } else {  // graph-ID skip fallback
      atomicAdd(&pooled[g * D_OUT + lane], val);
      if (lane == 0) atomicAdd(&cnt[g], 1.f);
    }
  }
  __syncthreads();
  for (int idx = tid; idx < POOL_ROWS * D_OUT; idx += 256) {
    int g = g0 + (idx >> 6);
    float v = lpool[idx];
    if (g < NGRAPH && v != 0.f) atomicAdd(&pooled[g * D_OUT + (idx & 63)], v);
  }
  if (tid < POOL_ROWS) {
    int g = g0 + tid;
    float v = lcnt[tid];
    if (g < NGRAPH && v != 0.f) atomicAdd(&cnt[g], v);
  }
}

// ---------------- head: mean-pool -> W3+BN+ReLU -> W4 ----------------
__global__ __launch_bounds__(256) void headK(const float* __restrict__ pooled,
    const float* __restrict__ cnt,
    const float* __restrict__ W3, const float* __restrict__ b3,
    const float* __restrict__ g2, const float* __restrict__ be2,
    const float* __restrict__ m2, const float* __restrict__ v2,
    const float* __restrict__ W4, const float* __restrict__ b4,
    float* __restrict__ out) {
  __shared__ float P[64 * 65];
  __shared__ float O[64 * 65];
  const int tid = threadIdx.x;
  for (int idx = tid; idx < NGRAPH * D_OUT; idx += 256) {
    int g = idx >> 6, d = idx & 63;
    P[g * 65 + d] = pooled[idx] / fmaxf(cnt[g], 1.f);
  }
  __syncthreads();
  const int g = tid & 63;
  const int j0 = (tid >> 6) * 16;
  for (int j = j0; j < j0 + 16; ++j) {
    float acc = 0.f;
    #pragma unroll 4
    for (int d = 0; d < 64; ++d) acc += P[g * 65 + d] * W3[d * 64 + j];
    float A = g2[j] * rsqrtf(v2[j] + BN_EPS);
    float val = (acc + b3[j] - m2[j]) * A + be2[j];
    O[g * 65 + j] = fmaxf(val, 0.f);
  }
  __syncthreads();
  if (tid < 64) {
    float acc = 0.f;
    #pragma unroll 4
    for (int jj = 0; jj < 64; ++jj) acc += O[tid * 65 + jj] * W4[jj];
    out[tid] = acc + b4[0];
  }
}

extern "C" void kernel_launch(void* const* d_in, const int* in_sizes, int n_in,
                              void* d_out, int out_size, void* d_ws, size_t ws_size,
                              hipStream_t stream) {
  const float* x   = (const float*)d_in[0];
  const float* ea  = (const float*)d_in[1];
  const float* W1  = (const float*)d_in[2];
  const float* b1  = (const float*)d_in[3];
  const float* g1  = (const float*)d_in[4];
  const float* be1 = (const float*)d_in[5];
  const float* m1  = (const float*)d_in[6];
  const float* v1  = (const float*)d_in[7];
  const float* W2  = (const float*)d_in[8];
  const float* b2  = (const float*)d_in[9];
  const float* W3  = (const float*)d_in[10];
  const float* b3  = (const float*)d_in[11];
  const float* g2  = (const float*)d_in[12];
  const float* be2 = (const float*)d_in[13];
  const float* m2  = (const float*)d_in[14];
  const float* v2  = (const float*)d_in[15];
  const float* W4  = (const float*)d_in[16];
  const float* b4  = (const float*)d_in[17];
  const int* ei    = (const int*)d_in[18];
  const int* batch = (const int*)d_in[19];
  const int n = in_sizes[0] / D_IN;
  const int E = in_sizes[1];
  float* out = (float*)d_out;

  char* w = (char*)d_ws;
  auto alloc = [&](size_t bytes) {
    char* p = w;
    w += (bytes + 255) & ~(size_t)255;
    return p;
  };
  unsigned short* h1b = (unsigned short*)alloc((size_t)n * D_HID * 2);  // 25.6 MB bf16
  unsigned short* h2b = (unsigned short*)alloc((size_t)n * D_OUT * 2);  // 6.4 MB bf16
  unsigned short* w1t = (unsigned short*)alloc((size_t)D_IN * D_HID * 2);
  unsigned short* w2t = (unsigned short*)alloc((size_t)D_HID * D_OUT * 2);
  int*   outdeg = (int*)  alloc((size_t)n * 4);
  int*   indeg  = (int*)  alloc((size_t)n * 4);
  int*   ptr    = (int*)  alloc((size_t)n * 4);
  int*   pos    = (int*)  alloc((size_t)n * 4);
  int2*  csr    = (int2*) alloc((size_t)(E + n) * 8);
  float* pooled = (float*)alloc((size_t)NGRAPH * D_OUT * 4);
  float* cnt    = (float*)alloc((size_t)NGRAPH * 4);
  int*   counter= (int*)  alloc(4);

  initK<<<(n + 255) / 256, 256, 0, stream>>>(outdeg, indeg, pooled, cnt, counter, n);
  countK<<<(E + 255) / 256, 256, 0, stream>>>(ei, outdeg, indeg, E);
  allocK<<<(n + 255) / 256, 256, 0, stream>>>(indeg, ptr, pos, counter, n);
  fillK<<<(E + n + 255) / 256, 256, 0, stream>>>(ei, ea, outdeg, pos, csr, E, n);
  prepK<<<(D_IN * D_HID + 255) / 256, 256, 0, stream>>>(W1, W2, w1t, w2t);
  dim3 g1grid((n + 63) / 64, 2);
  gemm1M<<<g1grid, 256, 0, stream>>>(x, w1t, b1, g1, be1, m1, v1, h1b, n);
  gemm2M<<<(n + 63) / 64, 256, 0, stream>>>(h1b, w2t, b2, h2b, n);
  aggK<<<(n + AGG_NPB - 1) / AGG_NPB, 256, 0, stream>>>(h2b, ptr, indeg, outdeg, csr, batch, pooled, cnt, n);
  headK<<<1, 256, 0, stream>>>(pooled, cnt, W3, b3, g2, be2, m2, v2, W4, b4, out);
}

// Round 13
// 360.041 us; speedup vs baseline: 1.1236x; 1.1236x over previous
//
#include <hip/hip_runtime.h>

#define D_IN 128
#define D_HID 256
#define D_OUT 64
#define NGRAPH 64
#define BN_EPS 1e-5f
#define AGG_NPB 8   // nodes per block = 8 waves x 1 node/wave (512 threads)
#define POOL_ROWS 8 // LDS pool rows (graph span safety)

typedef __attribute__((ext_vector_type(8))) short bf16x8;
typedef __attribute__((ext_vector_type(4))) float f32x4;

__device__ inline unsigned short f2bf(float f) {
  unsigned u = __float_as_uint(f);
  return (unsigned short)((u + 0x7FFFu + ((u >> 16) & 1u)) >> 16);  // RNE
}
__device__ inline float bf2f(unsigned short h) {
  return __uint_as_float((unsigned)h << 16);
}

// ------- init: deg=1, zero pooled/cnt/counter, and bf16-transpose weights -------
__global__ void initK(int* outdeg, int* indeg, float* pooled, float* cnt, int* counter,
                      const float* __restrict__ W1, const float* __restrict__ W2,
                      unsigned short* __restrict__ w1t, unsigned short* __restrict__ w2t, int n) {
  int i = blockIdx.x * blockDim.x + threadIdx.x;
  if (i < n) { outdeg[i] = 1; indeg[i] = 1; }
  if (i < NGRAPH * D_OUT) pooled[i] = 0.f;
  if (i < NGRAPH) cnt[i] = 0.f;
  if (i == 0) *counter = 0;
  if (i < D_IN * D_HID)  { int k = i >> 8, c = i & 255; w1t[c * D_IN + k]  = f2bf(W1[i]); }
  if (i < D_HID * D_OUT) { int k = i >> 6, c = i & 63;  w2t[c * D_HID + k] = f2bf(W2[i]); }
}

// ---------------- degree count ----------------
__global__ void countK(const int* __restrict__ ei, int* outdeg, int* indeg, int E) {
  int e = blockIdx.x * blockDim.x + threadIdx.x;
  if (e >= E) return;
  atomicAdd(&outdeg[ei[e]], 1);      // row (out-degree, GCN norm base)
  atomicAdd(&indeg[ei[E + e]], 1);   // col (CSR segment length)
}

// ---------------- CSR range allocation: wave-scan + 1 atomic per wave ----------------
__global__ void allocK(const int* __restrict__ indeg, int* ptr, int* pos, int* counter, int n) {
  int i = blockIdx.x * blockDim.x + threadIdx.x;
  int lane = threadIdx.x & 63;
  int l = (i < n) ? indeg[i] : 0;
  int s = l;
  #pragma unroll
  for (int o = 1; o < 64; o <<= 1) {
    int v = __shfl_up(s, o);
    if (lane >= o) s += v;
  }
  int base = 0;
  if (lane == 63) base = atomicAdd(counter, s);  // lane63's inclusive = wave total
  base = __shfl(base, 63);
  if (i < n) { ptr[i] = base + s - l; pos[i] = base + s - l; }
}

// ---------------- CSR fill (edges + self loops), packed int2 {src, w-bits} ----
__global__ void fillK(const int* __restrict__ ei, const float* __restrict__ ea,
                      const int* __restrict__ outdeg, int* pos,
                      int2* __restrict__ csr, int E, int n) {
  int t = blockIdx.x * blockDim.x + threadIdx.x;
  if (t >= E + n) return;
  int r, c; float w;
  if (t < E) {
    r = ei[t]; c = ei[E + t];
    w = rsqrtf((float)outdeg[r]) * ea[t];
  } else {
    r = c = t - E;
    w = rsqrtf((float)outdeg[r]);   // self loop: ea = 1
  }
  int slot = atomicAdd(&pos[c], 1);
  csr[slot] = make_int2(r, __float_as_int(w));
}

// ---------------- GEMM1 (bf16 MFMA) fused BN+ReLU: h1b = relu(bn(x@W1+b1)) ----
__global__ __launch_bounds__(256) void gemm1M(const float* __restrict__ x,
    const unsigned short* __restrict__ w1t,
    const float* __restrict__ b1, const float* __restrict__ g1,
    const float* __restrict__ be1, const float* __restrict__ m1, const float* __restrict__ v1,
    unsigned short* __restrict__ h1b, int n) {
  __shared__ __align__(16) short xs[64 * 128];
  __shared__ __align__(16) short ws[128 * 128];
  const int tid = threadIdx.x;
  const int row0 = blockIdx.x * 64;
  const int col0 = blockIdx.y * 128;
  #pragma unroll
  for (int it = 0; it < 4; ++it) {
    int id = it * 256 + tid;
    int r = id >> 4, c = id & 15;
    int gr = row0 + r;
    float f[8];
    if (gr < n) {
      float4 v0 = *(const float4*)&x[(size_t)gr * D_IN + c * 8];
      float4 v1 = *(const float4*)&x[(size_t)gr * D_IN + c * 8 + 4];
      f[0]=v0.x; f[1]=v0.y; f[2]=v0.z; f[3]=v0.w;
      f[4]=v1.x; f[5]=v1.y; f[6]=v1.z; f[7]=v1.w;
    } else {
      #pragma unroll
      for (int j = 0; j < 8; ++j) f[j] = 0.f;
    }
    bf16x8 pv;
    #pragma unroll
    for (int j = 0; j < 8; ++j) pv[j] = (short)f2bf(f[j]);
    *(bf16x8*)&xs[r * 128 + (c ^ (r & 15)) * 8] = pv;
  }
  #pragma unroll
  for (int it = 0; it < 8; ++it) {
    int id = it * 256 + tid;
    int r = id >> 4, c = id & 15;
    uint4 v = *(const uint4*)&w1t[(size_t)(col0 + r) * D_IN + c * 8];
    *(uint4*)&ws[r * 128 + (c ^ (r & 15)) * 8] = v;
  }
  __syncthreads();
  const int w = tid >> 6, l = tid & 63;
  const int m = l & 15, g = l >> 4;
  const int rbase = w * 16;
  f32x4 acc[8];
  #pragma unroll
  for (int i = 0; i < 8; ++i) acc[i] = (f32x4){0.f, 0.f, 0.f, 0.f};
  #pragma unroll
  for (int ks = 0; ks < 4; ++ks) {
    int ch = (ks * 4 + g) ^ m;
    bf16x8 A = *(bf16x8*)&xs[(rbase + m) * 128 + ch * 8];
    #pragma unroll
    for (int nt = 0; nt < 8; ++nt) {
      bf16x8 B = *(bf16x8*)&ws[(nt * 16 + m) * 128 + ch * 8];
      acc[nt] = __builtin_amdgcn_mfma_f32_16x16x32_bf16(A, B, acc[nt], 0, 0, 0);
    }
  }
  #pragma unroll
  for (int nt = 0; nt < 8; ++nt) {
    int c = col0 + nt * 16 + m;
    float As = g1[c] * rsqrtf(v1[c] + BN_EPS);
    float Bs = be1[c] + (b1[c] - m1[c]) * As;
    #pragma unroll
    for (int i = 0; i < 4; ++i) {
      int gr = row0 + rbase + g * 4 + i;
      if (gr < n) {
        float val = fmaxf(acc[nt][i] * As + Bs, 0.f);
        h1b[(size_t)gr * D_HID + c] = f2bf(val);
      }
    }
  }
}

// ---------------- GEMM2 (bf16 MFMA): h2b = bf16(h1b @ W2 + b2) ----------------
__global__ __launch_bounds__(256) void gemm2M(const unsigned short* __restrict__ h1b,
    const unsigned short* __restrict__ w2t, const float* __restrict__ b2,
    unsigned short* __restrict__ h2b, int n) {
  __shared__ __align__(16) short hs[64 * 128];
  __shared__ __align__(16) short ws[64 * 128];
  const int tid = threadIdx.x;
  const int row0 = blockIdx.x * 64;
  const int w = tid >> 6, l = tid & 63;
  const int m = l & 15, g = l >> 4;
  const int rbase = w * 16;
  f32x4 acc[4];
  #pragma unroll
  for (int i = 0; i < 4; ++i) acc[i] = (f32x4){0.f, 0.f, 0.f, 0.f};
  for (int ph = 0; ph < 2; ++ph) {
    int kbase = ph * 128;
    __syncthreads();
    #pragma unroll
    for (int it = 0; it < 4; ++it) {
      int id = it * 256 + tid;
      int r = id >> 4, c = id & 15;
      int gr = row0 + r;
      uint4 v = (uint4){0u, 0u, 0u, 0u};
      if (gr < n) v = *(const uint4*)&h1b[(size_t)gr * D_HID + kbase + c * 8];
      *(uint4*)&hs[r * 128 + (c ^ (r & 15)) * 8] = v;
    }
    #pragma unroll
    for (int it = 0; it < 4; ++it) {
      int id = it * 256 + tid;
      int r = id >> 4, c = id & 15;
      uint4 v = *(const uint4*)&w2t[(size_t)r * D_HID + kbase + c * 8];
      *(uint4*)&ws[r * 128 + (c ^ (r & 15)) * 8] = v;
    }
    __syncthreads();
    #pragma unroll
    for (int ks = 0; ks < 4; ++ks) {
      int ch = (ks * 4 + g) ^ m;
      bf16x8 A = *(bf16x8*)&hs[(rbase + m) * 128 + ch * 8];
      #pragma unroll
      for (int nt = 0; nt < 4; ++nt) {
        bf16x8 B = *(bf16x8*)&ws[(nt * 16 + m) * 128 + ch * 8];
        acc[nt] = __builtin_amdgcn_mfma_f32_16x16x32_bf16(A, B, acc[nt], 0, 0, 0);
      }
    }
  }
  #pragma unroll
  for (int nt = 0; nt < 4; ++nt) {
    int c = nt * 16 + m;
    float bb = b2[c];
    #pragma unroll
    for (int i = 0; i < 4; ++i) {
      int gr = row0 + rbase + g * 4 + i;
      if (gr < n) h2b[(size_t)gr * D_OUT + c] = f2bf(acc[nt][i] + bb);
    }
  }
}

// ------- aggregate: 1 node/wave, 8-deep pipelined gather (csr prefetch) -------
__global__ __launch_bounds__(512) void aggK(const unsigned short* __restrict__ h2b,
    const int* __restrict__ ptr, const int* __restrict__ indeg, const int* __restrict__ outdeg,
    const int2* __restrict__ csr, const int* __restrict__ batch,
    float* __restrict__ pooled, float* __restrict__ cnt, int n) {
  __shared__ float lpool[POOL_ROWS * D_OUT];
  __shared__ float lcnt[POOL_ROWS];
  const int tid = threadIdx.x;
  for (int i = tid; i < POOL_ROWS * D_OUT; i += 512) lpool[i] = 0.f;
  if (tid < POOL_ROWS) lcnt[tid] = 0.f;
  const int n0 = blockIdx.x * AGG_NPB;
  const int g0 = batch[n0 < n ? n0 : (n - 1)];
  __syncthreads();
  const int wave = tid >> 6, lane = tid & 63;
  const int i = n0 + wave;
  if (i < n) {
    const int start = ptr[i];
    const int len = indeg[i];
    const int last = start + len - 1;
    float acc = 0.f;
    // prologue: csr chunk 0 (clamped)
    int2 e[8];
    #pragma unroll
    for (int j = 0; j < 8; ++j) e[j] = csr[min(start + j, last)];
    for (int s0 = 0; s0 < len; s0 += 8) {
      // issue 8 independent gathers (addresses always valid via clamp)
      unsigned short h[8]; float w[8];
      #pragma unroll
      for (int j = 0; j < 8; ++j) {
        w[j] = (s0 + j < len) ? __int_as_float(e[j].y) : 0.f;
        h[j] = h2b[(size_t)e[j].x * D_OUT + lane];
      }
      // prefetch next csr chunk while gathers are in flight
      #pragma unroll
      for (int j = 0; j < 8; ++j) e[j] = csr[min(start + s0 + 8 + j, last)];
      #pragma unroll
      for (int j = 0; j < 8; ++j) acc = fmaf(w[j], bf2f(h[j]), acc);
    }
    float val = fmaxf(acc * rsqrtf((float)outdeg[i]), 0.f);
    int g = batch[i];
    int gl = g - g0;
    if (gl < POOL_ROWS) {
      atomicAdd(&lpool[gl * D_OUT + lane], val);
      if (lane == 0) atomicAdd(&lcnt[gl], 1.f);
    } else {  // pathological graph-span fallback
      atomicAdd(&pooled[g * D_OUT + lane], val);
      if (lane == 0) atomicAdd(&cnt[g], 1.f);
    }
  }
  __syncthreads();
  for (int idx = tid; idx < POOL_ROWS * D_OUT; idx += 512) {
    int g = g0 + (idx >> 6);
    float v = lpool[idx];
    if (g < NGRAPH && v != 0.f) atomicAdd(&pooled[g * D_OUT + (idx & 63)], v);
  }
  if (tid < POOL_ROWS) {
    int g = g0 + tid;
    float v = lcnt[tid];
    if (g < NGRAPH && v != 0.f) atomicAdd(&cnt[g], v);
  }
}

// ---------------- head: mean-pool -> W3+BN+ReLU -> W4 ----------------
__global__ __launch_bounds__(256) void headK(const float* __restrict__ pooled,
    const float* __restrict__ cnt,
    const float* __restrict__ W3, const float* __restrict__ b3,
    const float* __restrict__ g2, const float* __restrict__ be2,
    const float* __restrict__ m2, const float* __restrict__ v2,
    const float* __restrict__ W4, const float* __restrict__ b4,
    float* __restrict__ out) {
  __shared__ float P[64 * 65];
  __shared__ float O[64 * 65];
  const int tid = threadIdx.x;
  for (int idx = tid; idx < NGRAPH * D_OUT; idx += 256) {
    int g = idx >> 6, d = idx & 63;
    P[g * 65 + d] = pooled[idx] / fmaxf(cnt[g], 1.f);
  }
  __syncthreads();
  const int g = tid & 63;
  const int j0 = (tid >> 6) * 16;
  for (int j = j0; j < j0 + 16; ++j) {
    float acc = 0.f;
    #pragma unroll 4
    for (int d = 0; d < 64; ++d) acc += P[g * 65 + d] * W3[d * 64 + j];
    float A = g2[j] * rsqrtf(v2[j] + BN_EPS);
    float val = (acc + b3[j] - m2[j]) * A + be2[j];
    O[g * 65 + j] = fmaxf(val, 0.f);
  }
  __syncthreads();
  if (tid < 64) {
    float acc = 0.f;
    #pragma unroll 4
    for (int jj = 0; jj < 64; ++jj) acc += O[tid * 65 + jj] * W4[jj];
    out[tid] = acc + b4[0];
  }
}

extern "C" void kernel_launch(void* const* d_in, const int* in_sizes, int n_in,
                              void* d_out, int out_size, void* d_ws, size_t ws_size,
                              hipStream_t stream) {
  const float* x   = (const float*)d_in[0];
  const float* ea  = (const float*)d_in[1];
  const float* W1  = (const float*)d_in[2];
  const float* b1  = (const float*)d_in[3];
  const float* g1  = (const float*)d_in[4];
  const float* be1 = (const float*)d_in[5];
  const float* m1  = (const float*)d_in[6];
  const float* v1  = (const float*)d_in[7];
  const float* W2  = (const float*)d_in[8];
  const float* b2  = (const float*)d_in[9];
  const float* W3  = (const float*)d_in[10];
  const float* b3  = (const float*)d_in[11];
  const float* g2  = (const float*)d_in[12];
  const float* be2 = (const float*)d_in[13];
  const float* m2  = (const float*)d_in[14];
  const float* v2  = (const float*)d_in[15];
  const float* W4  = (const float*)d_in[16];
  const float* b4  = (const float*)d_in[17];
  const int* ei    = (const int*)d_in[18];
  const int* batch = (const int*)d_in[19];
  const int n = in_sizes[0] / D_IN;
  const int E = in_sizes[1];
  float* out = (float*)d_out;

  char* w = (char*)d_ws;
  auto alloc = [&](size_t bytes) {
    char* p = w;
    w += (bytes + 255) & ~(size_t)255;
    return p;
  };
  unsigned short* h1b = (unsigned short*)alloc((size_t)n * D_HID * 2);  // 25.6 MB bf16
  unsigned short* h2b = (unsigned short*)alloc((size_t)n * D_OUT * 2);  // 6.4 MB bf16
  unsigned short* w1t = (unsigned short*)alloc((size_t)D_IN * D_HID * 2);
  unsigned short* w2t = (unsigned short*)alloc((size_t)D_HID * D_OUT * 2);
  int*   outdeg = (int*)  alloc((size_t)n * 4);
  int*   indeg  = (int*)  alloc((size_t)n * 4);
  int*   ptr    = (int*)  alloc((size_t)n * 4);
  int*   pos    = (int*)  alloc((size_t)n * 4);
  int2*  csr    = (int2*) alloc((size_t)(E + n) * 8);
  float* pooled = (float*)alloc((size_t)NGRAPH * D_OUT * 4);
  float* cnt    = (float*)alloc((size_t)NGRAPH * 4);
  int*   counter= (int*)  alloc(4);

  initK<<<(n + 255) / 256, 256, 0, stream>>>(outdeg, indeg, pooled, cnt, counter, W1, W2, w1t, w2t, n);
  countK<<<(E + 255) / 256, 256, 0, stream>>>(ei, outdeg, indeg, E);
  allocK<<<(n + 255) / 256, 256, 0, stream>>>(indeg, ptr, pos, counter, n);
  fillK<<<(E + n + 255) / 256, 256, 0, stream>>>(ei, ea, outdeg, pos, csr, E, n);
  dim3 g1grid((n + 63) / 64, 2);
  gemm1M<<<g1grid, 256, 0, stream>>>(x, w1t, b1, g1, be1, m1, v1, h1b, n);
  gemm2M<<<(n + 63) / 64, 256, 0, stream>>>(h1b, w2t, b2, h2b, n);
  aggK<<<(n + AGG_NPB - 1) / AGG_NPB, 512, 0, stream>>>(h2b, ptr, indeg, outdeg, csr, batch, pooled, cnt, n);
  headK<<<1, 256, 0, stream>>>(pooled, cnt, W3, b3, g2, be2, m2, v2, W4, b4, out);
}